// Round 2
// baseline (24229.948 us; speedup 1.0000x reference)
//
#include <hip/hip_runtime.h>
#include <math.h>

#define Nn 50000
#define Ff 16
#define Tt 12
#define Hh 64
#define Ee 1600000
#define Cc 80  // F + H

static __device__ __forceinline__ float sigmoidf_(float x) { return 1.0f / (1.0f + expf(-x)); }

// ---------------- CSR build ----------------
__global__ void k_deg(const int* __restrict__ ei, const float* __restrict__ ew,
                      float* __restrict__ deg, int* __restrict__ cnt) {
  int e = blockIdx.x * blockDim.x + threadIdx.x;
  if (e >= Ee) return;
  int d = ei[Ee + e];
  atomicAdd(&deg[d], ew[e]);
  atomicAdd(&cnt[d], 1);
}

__global__ void k_dis(float* dd) {
  int i = blockIdx.x * blockDim.x + threadIdx.x;
  if (i >= Nn) return;
  dd[i] = 1.0f / sqrtf(dd[i] + 1.0f);  // rsqrt(deg + self-loop)
}

__global__ __launch_bounds__(1024) void k_scan(const int* __restrict__ cnt,
                                               int* __restrict__ rp, int* __restrict__ cur) {
  __shared__ int ss[1024];
  const int ITEMS = (Nn + 1023) / 1024;  // 49
  int t = threadIdx.x;
  int base = t * ITEMS;
  int sum = 0;
  for (int k = 0; k < ITEMS; k++) {
    int idx = base + k;
    if (idx < Nn) sum += cnt[idx];
  }
  ss[t] = sum;
  __syncthreads();
  for (int off = 1; off < 1024; off <<= 1) {
    int v = (t >= off) ? ss[t - off] : 0;
    __syncthreads();
    ss[t] += v;
    __syncthreads();
  }
  int run = ss[t] - sum;  // exclusive prefix
  for (int k = 0; k < ITEMS; k++) {
    int idx = base + k;
    if (idx < Nn) { rp[idx] = run; cur[idx] = run; run += cnt[idx]; }
  }
  if (t == 0) rp[Nn] = Ee;
}

__global__ void k_scatter(const int* __restrict__ ei, const float* __restrict__ ew,
                          const float* __restrict__ dis, int* __restrict__ cur,
                          int* __restrict__ csrc, float* __restrict__ cw) {
  int e = blockIdx.x * blockDim.x + threadIdx.x;
  if (e >= Ee) return;
  int s = ei[e];
  int d = ei[Ee + e];
  float w = ew[e] * dis[s] * dis[d];
  int pos = atomicAdd(&cur[d], 1);
  csrc[pos] = s;
  cw[pos] = w;
}

// ---------------- Px[t][i][f] = (A_hat @ x) for all t (x row = 192 contiguous floats) ----------------
__global__ __launch_bounds__(256) void k_agg_px(
    const float* __restrict__ x, float* __restrict__ Px,
    const int* __restrict__ rp, const int* __restrict__ csrc,
    const float* __restrict__ cw, const float* __restrict__ dis) {
  int i = blockIdx.x * 4 + (threadIdx.x >> 6);
  if (i >= Nn) return;
  int lane = threadIdx.x & 63;
  const int R = Ff * Tt;  // 192
  float d = dis[i];
  float sn = d * d;
  const float* xi = x + (size_t)i * R;
  float a0 = sn * xi[lane];
  float a1 = sn * xi[64 + lane];
  float a2 = sn * xi[128 + lane];
  int jb = rp[i], je = rp[i + 1];
  int j = jb;
  for (; j + 2 <= je; j += 2) {
    int s0 = csrc[j], s1 = csrc[j + 1];
    float w0 = cw[j], w1 = cw[j + 1];
    const float* x0 = x + (size_t)s0 * R;
    const float* x1 = x + (size_t)s1 * R;
    float u0 = x0[lane], u1 = x0[64 + lane], u2 = x0[128 + lane];
    float v0 = x1[lane], v1 = x1[64 + lane], v2 = x1[128 + lane];
    a0 = fmaf(w0, u0, a0); a1 = fmaf(w0, u1, a1); a2 = fmaf(w0, u2, a2);
    a0 = fmaf(w1, v0, a0); a1 = fmaf(w1, v1, a1); a2 = fmaf(w1, v2, a2);
  }
  for (; j < je; j++) {
    int s = csrc[j];
    float w = cw[j];
    const float* xr = x + (size_t)s * R;
    a0 = fmaf(w, xr[lane], a0);
    a1 = fmaf(w, xr[64 + lane], a1);
    a2 = fmaf(w, xr[128 + lane], a2);
  }
#pragma unroll
  for (int k = 0; k < 3; k++) {
    int c = lane + 64 * k;      // c = f*T + t within the x row
    int f = c / Tt, tt = c % Tt;
    float val = (k == 0) ? a0 : (k == 1 ? a1 : a2);
    Px[(size_t)tt * Nn * Ff + (size_t)i * Ff + f] = val;
  }
}

// ---------------- fused: agg(h) + z/r GEMM ----------------
// block = 512 (8 waves); each wave owns 4 nodes; lane = channel
__global__ __launch_bounds__(512, 4) void k_zr(
    const float* __restrict__ Px, const float* __restrict__ h,
    const int* __restrict__ rp, const int* __restrict__ csrc,
    const float* __restrict__ cw, const float* __restrict__ dis,
    const float* __restrict__ Wz, const float* __restrict__ bz,
    const float* __restrict__ Wr, const float* __restrict__ br,
    float* __restrict__ zb, float* __restrict__ rhb, int tstep) {
  __shared__ float sWz[Cc * Hh];     // 20 KB
  __shared__ float sWr[Cc * Hh];     // 20 KB
  __shared__ float sXC[8][4][Cc];    // 10 KB  [wave][node][c]
  const int tid = threadIdx.x;
  {
    const float4* wz4 = (const float4*)Wz;
    const float4* wr4 = (const float4*)Wr;
    float4* sz4 = (float4*)sWz;
    float4* sr4 = (float4*)sWr;
    for (int q = tid; q < (Cc * Hh) / 4; q += 512) { sz4[q] = wz4[q]; sr4[q] = wr4[q]; }
  }
  __syncthreads();
  const int wv = tid >> 6, o = tid & 63;
  const int i0 = blockIdx.x * 32 + wv * 4;
  const float* Pxt = Px + (size_t)tstep * Nn * Ff;
  float hself[4];
  // phase A: aggregate h, stage xc rows into LDS
#pragma unroll
  for (int nd = 0; nd < 4; nd++) {
    int i = i0 + nd;
    float acc = 0.f, hv = 0.f, pxv = 0.f;
    if (i < Nn) {
      float d = dis[i];
      hv = h[(size_t)i * Hh + o];
      acc = d * d * hv;
      int jb = rp[i], je = rp[i + 1];
      int j = jb;
      for (; j + 4 <= je; j += 4) {
        int s0 = csrc[j], s1 = csrc[j + 1], s2 = csrc[j + 2], s3 = csrc[j + 3];
        float w0 = cw[j], w1 = cw[j + 1], w2 = cw[j + 2], w3 = cw[j + 3];
        float v0 = h[(size_t)s0 * Hh + o];
        float v1 = h[(size_t)s1 * Hh + o];
        float v2 = h[(size_t)s2 * Hh + o];
        float v3 = h[(size_t)s3 * Hh + o];
        acc = fmaf(w0, v0, acc); acc = fmaf(w1, v1, acc);
        acc = fmaf(w2, v2, acc); acc = fmaf(w3, v3, acc);
      }
      for (; j < je; j++) acc = fmaf(cw[j], h[(size_t)csrc[j] * Hh + o], acc);
      if (o < Ff) pxv = Pxt[(size_t)i * Ff + o];
    }
    if (o < Ff) sXC[wv][nd][o] = pxv;
    sXC[wv][nd][Ff + o] = acc;
    hself[nd] = hv;
  }
  // phase B: GEMM (weights from LDS, xc broadcast from LDS)
  float az[4] = {0, 0, 0, 0}, ar[4] = {0, 0, 0, 0};
  for (int c = 0; c < Cc; c += 4) {
    float z0 = sWz[(c + 0) * Hh + o], z1 = sWz[(c + 1) * Hh + o];
    float z2 = sWz[(c + 2) * Hh + o], z3 = sWz[(c + 3) * Hh + o];
    float r0 = sWr[(c + 0) * Hh + o], r1 = sWr[(c + 1) * Hh + o];
    float r2 = sWr[(c + 2) * Hh + o], r3 = sWr[(c + 3) * Hh + o];
#pragma unroll
    for (int nd = 0; nd < 4; nd++) {
      const float4 xv = *(const float4*)&sXC[wv][nd][c];
      az[nd] = fmaf(xv.x, z0, fmaf(xv.y, z1, fmaf(xv.z, z2, fmaf(xv.w, z3, az[nd]))));
      ar[nd] = fmaf(xv.x, r0, fmaf(xv.y, r1, fmaf(xv.z, r2, fmaf(xv.w, r3, ar[nd]))));
    }
  }
  float bzo = bz[o], bro = br[o];
#pragma unroll
  for (int nd = 0; nd < 4; nd++) {
    int i = i0 + nd;
    if (i < Nn) {
      float zv = sigmoidf_(az[nd] + bzo);
      float rv = sigmoidf_(ar[nd] + bro);
      zb[(size_t)i * Hh + o] = zv;
      rhb[(size_t)i * Hh + o] = rv * hself[nd];
    }
  }
}

// ---------------- fused: agg(r*h) + h GEMM + GRU update + online-softmax attention ----------------
__global__ __launch_bounds__(512, 4) void k_h(
    const float* __restrict__ Px, const float* __restrict__ rhb,
    const float* __restrict__ zb, float* __restrict__ h,
    const int* __restrict__ rp, const int* __restrict__ csrc,
    const float* __restrict__ cw, const float* __restrict__ dis,
    const float* __restrict__ Wh, const float* __restrict__ bh,
    const float* __restrict__ Wa, const float* __restrict__ ba,
    const float* __restrict__ cv,
    float* __restrict__ mbuf, float* __restrict__ sbuf, float* __restrict__ ctx,
    int tstep) {
  __shared__ float sWh[Cc * Hh];     // 20 KB
  __shared__ float sWa[Hh * Hh];     // 16 KB
  __shared__ float sXC[8][4][Cc];    // 10 KB
  const int tid = threadIdx.x;
  {
    const float4* w4 = (const float4*)Wh;
    float4* s4 = (float4*)sWh;
    for (int q = tid; q < (Cc * Hh) / 4; q += 512) s4[q] = w4[q];
    const float4* a4 = (const float4*)Wa;
    float4* sa4 = (float4*)sWa;
    for (int q = tid; q < (Hh * Hh) / 4; q += 512) sa4[q] = a4[q];
  }
  __syncthreads();
  const int wv = tid >> 6, o = tid & 63;
  const int i0 = blockIdx.x * 32 + wv * 4;
  const float* Pxt = Px + (size_t)tstep * Nn * Ff;
  // phase A: aggregate rhb, stage xc rows
#pragma unroll
  for (int nd = 0; nd < 4; nd++) {
    int i = i0 + nd;
    float acc = 0.f, pxv = 0.f;
    if (i < Nn) {
      float d = dis[i];
      acc = d * d * rhb[(size_t)i * Hh + o];
      int jb = rp[i], je = rp[i + 1];
      int j = jb;
      for (; j + 4 <= je; j += 4) {
        int s0 = csrc[j], s1 = csrc[j + 1], s2 = csrc[j + 2], s3 = csrc[j + 3];
        float w0 = cw[j], w1 = cw[j + 1], w2 = cw[j + 2], w3 = cw[j + 3];
        float v0 = rhb[(size_t)s0 * Hh + o];
        float v1 = rhb[(size_t)s1 * Hh + o];
        float v2 = rhb[(size_t)s2 * Hh + o];
        float v3 = rhb[(size_t)s3 * Hh + o];
        acc = fmaf(w0, v0, acc); acc = fmaf(w1, v1, acc);
        acc = fmaf(w2, v2, acc); acc = fmaf(w3, v3, acc);
      }
      for (; j < je; j++) acc = fmaf(cw[j], rhb[(size_t)csrc[j] * Hh + o], acc);
      if (o < Ff) pxv = Pxt[(size_t)i * Ff + o];
    }
    if (o < Ff) sXC[wv][nd][o] = pxv;
    sXC[wv][nd][Ff + o] = acc;
  }
  // phase B: GEMM → candidate pre-activation
  float ah[4] = {0, 0, 0, 0};
  for (int c = 0; c < Cc; c += 4) {
    float w0 = sWh[(c + 0) * Hh + o], w1 = sWh[(c + 1) * Hh + o];
    float w2 = sWh[(c + 2) * Hh + o], w3 = sWh[(c + 3) * Hh + o];
#pragma unroll
    for (int nd = 0; nd < 4; nd++) {
      const float4 xv = *(const float4*)&sXC[wv][nd][c];
      ah[nd] = fmaf(xv.x, w0, fmaf(xv.y, w1, fmaf(xv.z, w2, fmaf(xv.w, w3, ah[nd]))));
    }
  }
  // GRU update; store h_new to global + LDS (for attention broadcast)
  float bho = bh[o];
  float hnreg[4];
#pragma unroll
  for (int nd = 0; nd < 4; nd++) {
    int i = i0 + nd;
    float hn = 0.f;
    if (i < Nn) {
      float hc = tanhf(ah[nd] + bho);
      float zv = zb[(size_t)i * Hh + o];
      float hv = h[(size_t)i * Hh + o];
      hn = zv * hv + (1.0f - zv) * hc;
      h[(size_t)i * Hh + o] = hn;
    }
    sXC[wv][nd][Ff + o] = hn;  // reuse LDS row (GEMM done)
    hnreg[nd] = hn;
  }
  // phase C: attention score = tanh(hn @ Wa + ba), align = score . cv
  float sc[4] = {0, 0, 0, 0};
  for (int c = 0; c < Hh; c += 4) {
    float a0 = sWa[(c + 0) * Hh + o], a1 = sWa[(c + 1) * Hh + o];
    float a2 = sWa[(c + 2) * Hh + o], a3 = sWa[(c + 3) * Hh + o];
#pragma unroll
    for (int nd = 0; nd < 4; nd++) {
      const float4 hv4 = *(const float4*)&sXC[wv][nd][Ff + c];
      sc[nd] = fmaf(hv4.x, a0, fmaf(hv4.y, a1, fmaf(hv4.z, a2, fmaf(hv4.w, a3, sc[nd]))));
    }
  }
  float bao = ba[o], cvo = cv[o];
#pragma unroll
  for (int nd = 0; nd < 4; nd++) {
    float ap = tanhf(sc[nd] + bao) * cvo;
#pragma unroll
    for (int off = 32; off >= 1; off >>= 1) ap += __shfl_xor(ap, off, 64);
    int i = i0 + nd;
    if (i < Nn) {
      if (tstep == 0) {
        ctx[(size_t)i * Hh + o] = hnreg[nd];
        if (o == 0) { mbuf[i] = ap; sbuf[i] = 1.0f; }
      } else {
        float mo = mbuf[i];
        float so = sbuf[i];
        float mn = fmaxf(mo, ap);
        float scl = expf(mo - mn);
        float p = expf(ap - mn);
        ctx[(size_t)i * Hh + o] = ctx[(size_t)i * Hh + o] * scl + p * hnreg[nd];
        if (o == 0) { mbuf[i] = mn; sbuf[i] = so * scl + p; }
      }
    }
  }
}

// ---------------- output: out[i] = (ctx/s) . Wfc + bfc ----------------
__global__ __launch_bounds__(256) void k_out(
    const float* __restrict__ ctx, const float* __restrict__ sbuf,
    const float* __restrict__ Wfc, const float* __restrict__ bfc,
    float* __restrict__ out) {
  int i = blockIdx.x * 4 + (threadIdx.x >> 6);
  if (i >= Nn) return;
  int o = threadIdx.x & 63;
  float inv = 1.0f / sbuf[i];
  float p = ctx[(size_t)i * Hh + o] * inv * Wfc[o];
#pragma unroll
  for (int off = 32; off >= 1; off >>= 1) p += __shfl_xor(p, off, 64);
  if (o == 0) out[i] = p + bfc[0];
}

extern "C" void kernel_launch(void* const* d_in, const int* in_sizes, int n_in,
                              void* d_out, int out_size, void* d_ws, size_t ws_size,
                              hipStream_t stream) {
  const float* x   = (const float*)d_in[0];
  const int* ei    = (const int*)d_in[1];
  const float* ew  = (const float*)d_in[2];
  const float* Wz  = (const float*)d_in[3];
  const float* bz  = (const float*)d_in[4];
  const float* Wr  = (const float*)d_in[5];
  const float* br  = (const float*)d_in[6];
  const float* Wh  = (const float*)d_in[7];
  const float* bh  = (const float*)d_in[8];
  const float* Wa  = (const float*)d_in[9];
  const float* ba  = (const float*)d_in[10];
  const float* cv  = (const float*)d_in[11];
  const float* Wfc = (const float*)d_in[12];
  const float* bfc = (const float*)d_in[13];
  float* out = (float*)d_out;

  char* w = (char*)d_ws;
  auto alloc = [&](size_t bytes) {
    char* p = w;
    w += (bytes + 255) & ~(size_t)255;
    return p;
  };
  float* dis = (float*)alloc((size_t)Nn * 4);       // deg, then rsqrt in place
  int* cnt   = (int*)alloc((size_t)Nn * 4);
  int* rp    = (int*)alloc((size_t)(Nn + 1) * 4);
  int* cur   = (int*)alloc((size_t)Nn * 4);
  int* csrc  = (int*)alloc((size_t)Ee * 4);
  float* cw  = (float*)alloc((size_t)Ee * 4);
  float* Pxb = (float*)alloc((size_t)Tt * Nn * Ff * 4);
  float* h   = (float*)alloc((size_t)Nn * Hh * 4);
  float* zbf = (float*)alloc((size_t)Nn * Hh * 4);
  float* rhb = (float*)alloc((size_t)Nn * Hh * 4);
  float* mb  = (float*)alloc((size_t)Nn * 4);
  float* sb  = (float*)alloc((size_t)Nn * 4);
  float* ctx = (float*)alloc((size_t)Nn * Hh * 4);

  hipMemsetAsync(dis, 0, (size_t)Nn * 4, stream);
  hipMemsetAsync(cnt, 0, (size_t)Nn * 4, stream);
  hipMemsetAsync(h, 0, (size_t)Nn * Hh * 4, stream);

  k_deg<<<(Ee + 255) / 256, 256, 0, stream>>>(ei, ew, dis, cnt);
  k_dis<<<(Nn + 255) / 256, 256, 0, stream>>>(dis);
  k_scan<<<1, 1024, 0, stream>>>(cnt, rp, cur);
  k_scatter<<<(Ee + 255) / 256, 256, 0, stream>>>(ei, ew, dis, cur, csrc, cw);
  k_agg_px<<<(Nn + 3) / 4, 256, 0, stream>>>(x, Pxb, rp, csrc, cw, dis);

  const int gFus = (Nn + 31) / 32;  // 512-thread blocks, 32 nodes each
  for (int t = 0; t < Tt; t++) {
    k_zr<<<gFus, 512, 0, stream>>>(Pxb, h, rp, csrc, cw, dis, Wz, bz, Wr, br, zbf, rhb, t);
    k_h<<<gFus, 512, 0, stream>>>(Pxb, rhb, zbf, h, rp, csrc, cw, dis, Wh, bh, Wa, ba, cv,
                                  mb, sb, ctx, t);
  }
  k_out<<<(Nn + 3) / 4, 256, 0, stream>>>(ctx, sb, Wfc, bfc, out);
}

// Round 3
// 6478.262 us; speedup vs baseline: 3.7402x; 3.7402x over previous
//
#include <hip/hip_runtime.h>
#include <math.h>

#define Nn 50000
#define Ff 16
#define Tt 12
#define Hh 64
#define Ee 1600000
#define Cc 80  // F + H

static __device__ __forceinline__ float sigmoidf_(float x) { return 1.0f / (1.0f + expf(-x)); }

// ---------------- CSR build ----------------
__global__ void k_deg(const int* __restrict__ ei, const float* __restrict__ ew,
                      float* __restrict__ deg, int* __restrict__ cnt) {
  int e = blockIdx.x * blockDim.x + threadIdx.x;
  if (e >= Ee) return;
  int d = ei[Ee + e];
  atomicAdd(&deg[d], ew[e]);
  atomicAdd(&cnt[d], 1);
}

__global__ void k_dis(float* dd) {
  int i = blockIdx.x * blockDim.x + threadIdx.x;
  if (i >= Nn) return;
  dd[i] = 1.0f / sqrtf(dd[i] + 1.0f);  // rsqrt(deg + self-loop)
}

__global__ __launch_bounds__(1024) void k_scan(const int* __restrict__ cnt,
                                               int* __restrict__ rp, int* __restrict__ cur) {
  __shared__ int ss[1024];
  const int ITEMS = (Nn + 1023) / 1024;  // 49
  int t = threadIdx.x;
  int base = t * ITEMS;
  int sum = 0;
  for (int k = 0; k < ITEMS; k++) {
    int idx = base + k;
    if (idx < Nn) sum += cnt[idx];
  }
  ss[t] = sum;
  __syncthreads();
  for (int off = 1; off < 1024; off <<= 1) {
    int v = (t >= off) ? ss[t - off] : 0;
    __syncthreads();
    ss[t] += v;
    __syncthreads();
  }
  int run = ss[t] - sum;  // exclusive prefix
  for (int k = 0; k < ITEMS; k++) {
    int idx = base + k;
    if (idx < Nn) { rp[idx] = run; cur[idx] = run; run += cnt[idx]; }
  }
  if (t == 0) rp[Nn] = Ee;
}

__global__ void k_scatter(const int* __restrict__ ei, const float* __restrict__ ew,
                          const float* __restrict__ dis, int* __restrict__ cur,
                          int* __restrict__ csrc, float* __restrict__ cw) {
  int e = blockIdx.x * blockDim.x + threadIdx.x;
  if (e >= Ee) return;
  int s = ei[e];
  int d = ei[Ee + e];
  float w = ew[e] * dis[s] * dis[d];
  int pos = atomicAdd(&cur[d], 1);
  csrc[pos] = s;
  cw[pos] = w;
}

// ---------------- Px[t][i][f] = (A_hat @ x) for all t (x row = 192 contiguous floats) ----------------
__global__ __launch_bounds__(256) void k_agg_px(
    const float* __restrict__ x, float* __restrict__ Px,
    const int* __restrict__ rp, const int* __restrict__ csrc,
    const float* __restrict__ cw, const float* __restrict__ dis) {
  int i = blockIdx.x * 4 + (threadIdx.x >> 6);
  if (i >= Nn) return;
  int lane = threadIdx.x & 63;
  const int R = Ff * Tt;  // 192
  float d = dis[i];
  float sn = d * d;
  const float* xi = x + (size_t)i * R;
  float a0 = sn * xi[lane];
  float a1 = sn * xi[64 + lane];
  float a2 = sn * xi[128 + lane];
  int jb = rp[i], je = rp[i + 1];
  for (int j = jb; j < je; j++) {
    int s = csrc[j];
    float w = cw[j];
    const float* xr = x + (size_t)s * R;
    a0 = fmaf(w, xr[lane], a0);
    a1 = fmaf(w, xr[64 + lane], a1);
    a2 = fmaf(w, xr[128 + lane], a2);
  }
#pragma unroll
  for (int k = 0; k < 3; k++) {
    int c = lane + 64 * k;      // c = f*T + t within the x row
    int f = c / Tt, tt = c % Tt;
    float val = (k == 0) ? a0 : (k == 1 ? a1 : a2);
    Px[(size_t)tt * Nn * Ff + (size_t)i * Ff + f] = val;
  }
}

// out[i][:] = self_norm[i]*v[i][:] + sum_edges w*v[src][:]   (64 channels, lane=channel)
__global__ __launch_bounds__(256) void k_agg64(
    const float* __restrict__ v, float* __restrict__ outv,
    const int* __restrict__ rp, const int* __restrict__ csrc,
    const float* __restrict__ cw, const float* __restrict__ dis) {
  int i = blockIdx.x * 4 + (threadIdx.x >> 6);
  if (i >= Nn) return;
  int o = threadIdx.x & 63;
  float d = dis[i];
  float acc = d * d * v[(size_t)i * Hh + o];
  int jb = rp[i], je = rp[i + 1];
  for (int j = jb; j < je; j++) {
    int s = csrc[j];
    float w = cw[j];
    acc = fmaf(w, v[(size_t)s * Hh + o], acc);
  }
  outv[(size_t)i * Hh + o] = acc;
}

// ---------------- GEMM z/r (spill-free): 256 threads, 4 waves, 16 nodes/block ----------------
__global__ __launch_bounds__(256) void k_gemm_zr(
    const float* __restrict__ Px, const float* __restrict__ Ph,
    const float* __restrict__ h,
    const float* __restrict__ Wz, const float* __restrict__ bz,
    const float* __restrict__ Wr, const float* __restrict__ br,
    float* __restrict__ zb, float* __restrict__ rhb, int tstep) {
  __shared__ float sWz[Cc * Hh];    // 20 KB
  __shared__ float sWr[Cc * Hh];    // 20 KB
  __shared__ float sX[4][4][Cc];    // 5 KB  [wave][node][c]
  const int tid = threadIdx.x;
  const int i0 = blockIdx.x * 16;
  {
    const float4* wz4 = (const float4*)Wz;
    const float4* wr4 = (const float4*)Wr;
    float4* sz4 = (float4*)sWz;
    float4* sr4 = (float4*)sWr;
    for (int q = tid; q < (Cc * Hh) / 4; q += 256) { sz4[q] = wz4[q]; sr4[q] = wr4[q]; }
  }
  {
    float4* s4 = (float4*)&sX[0][0][0];
    const float4* px4 = (const float4*)(Px + (size_t)tstep * Nn * Ff);
    const float4* ph4 = (const float4*)Ph;
    for (int q = tid; q < 16 * 20; q += 256) {
      int n = q / 20, r = q % 20;
      int i = i0 + n;
      float4 v = make_float4(0.f, 0.f, 0.f, 0.f);
      if (i < Nn) v = (r < 4) ? px4[(size_t)i * 4 + r] : ph4[(size_t)i * 16 + (r - 4)];
      s4[q] = v;
    }
  }
  __syncthreads();
  const int wv = tid >> 6, o = tid & 63;
  float az[4] = {0, 0, 0, 0}, ar[4] = {0, 0, 0, 0};
  for (int c = 0; c < Cc; c += 4) {
    float z0 = sWz[(c + 0) * Hh + o], z1 = sWz[(c + 1) * Hh + o];
    float z2 = sWz[(c + 2) * Hh + o], z3 = sWz[(c + 3) * Hh + o];
    float r0 = sWr[(c + 0) * Hh + o], r1 = sWr[(c + 1) * Hh + o];
    float r2 = sWr[(c + 2) * Hh + o], r3 = sWr[(c + 3) * Hh + o];
#pragma unroll
    for (int nd = 0; nd < 4; nd++) {
      const float4 xv = *(const float4*)&sX[wv][nd][c];
      az[nd] = fmaf(xv.x, z0, fmaf(xv.y, z1, fmaf(xv.z, z2, fmaf(xv.w, z3, az[nd]))));
      ar[nd] = fmaf(xv.x, r0, fmaf(xv.y, r1, fmaf(xv.z, r2, fmaf(xv.w, r3, ar[nd]))));
    }
  }
  float bzo = bz[o], bro = br[o];
#pragma unroll
  for (int nd = 0; nd < 4; nd++) {
    int i = i0 + wv * 4 + nd;
    if (i < Nn) {
      float zv = sigmoidf_(az[nd] + bzo);
      float rv = sigmoidf_(ar[nd] + bro);
      float hv = h[(size_t)i * Hh + o];
      zb[(size_t)i * Hh + o] = zv;
      rhb[(size_t)i * Hh + o] = rv * hv;
    }
  }
}

// ---------------- GEMM h (spill-free): GRU update + online-softmax attention fused ----------------
__global__ __launch_bounds__(256) void k_gemm_h(
    const float* __restrict__ Px, const float* __restrict__ Prh,
    const float* __restrict__ zb, float* __restrict__ h,
    const float* __restrict__ Wh, const float* __restrict__ bh,
    const float* __restrict__ Wa, const float* __restrict__ ba,
    const float* __restrict__ cv,
    float* __restrict__ mbuf, float* __restrict__ sbuf, float* __restrict__ ctx,
    int tstep) {
  __shared__ float sWh[Cc * Hh];    // 20 KB
  __shared__ float sWa[Hh * Hh];    // 16 KB
  __shared__ float sX[4][4][Cc];    // 5 KB
  const int tid = threadIdx.x;
  const int i0 = blockIdx.x * 16;
  {
    const float4* w4 = (const float4*)Wh;
    float4* s4 = (float4*)sWh;
    for (int q = tid; q < (Cc * Hh) / 4; q += 256) s4[q] = w4[q];
    const float4* a4 = (const float4*)Wa;
    float4* sa4 = (float4*)sWa;
    for (int q = tid; q < (Hh * Hh) / 4; q += 256) sa4[q] = a4[q];
  }
  {
    float4* s4 = (float4*)&sX[0][0][0];
    const float4* px4 = (const float4*)(Px + (size_t)tstep * Nn * Ff);
    const float4* ph4 = (const float4*)Prh;
    for (int q = tid; q < 16 * 20; q += 256) {
      int n = q / 20, r = q % 20;
      int i = i0 + n;
      float4 v = make_float4(0.f, 0.f, 0.f, 0.f);
      if (i < Nn) v = (r < 4) ? px4[(size_t)i * 4 + r] : ph4[(size_t)i * 16 + (r - 4)];
      s4[q] = v;
    }
  }
  __syncthreads();
  const int wv = tid >> 6, o = tid & 63;
  float ah[4] = {0, 0, 0, 0};
  for (int c = 0; c < Cc; c += 4) {
    float w0 = sWh[(c + 0) * Hh + o], w1 = sWh[(c + 1) * Hh + o];
    float w2 = sWh[(c + 2) * Hh + o], w3 = sWh[(c + 3) * Hh + o];
#pragma unroll
    for (int nd = 0; nd < 4; nd++) {
      const float4 xv = *(const float4*)&sX[wv][nd][c];
      ah[nd] = fmaf(xv.x, w0, fmaf(xv.y, w1, fmaf(xv.z, w2, fmaf(xv.w, w3, ah[nd]))));
    }
  }
  // GRU update; store h_new to global + wave-private LDS row (reuse sX tail, GEMM done)
  float bho = bh[o];
  float hnreg[4];
#pragma unroll
  for (int nd = 0; nd < 4; nd++) {
    int i = i0 + wv * 4 + nd;
    float hn = 0.f;
    if (i < Nn) {
      float hc = tanhf(ah[nd] + bho);
      float zv = zb[(size_t)i * Hh + o];
      float hv = h[(size_t)i * Hh + o];
      hn = zv * hv + (1.0f - zv) * hc;
      h[(size_t)i * Hh + o] = hn;
    }
    sX[wv][nd][Ff + o] = hn;  // wave-private: no cross-wave readers
    hnreg[nd] = hn;
  }
  // attention: score = tanh(hn @ Wa + ba); align = score . cv; online softmax
  float sc[4] = {0, 0, 0, 0};
  for (int c = 0; c < Hh; c += 4) {
    float a0 = sWa[(c + 0) * Hh + o], a1 = sWa[(c + 1) * Hh + o];
    float a2 = sWa[(c + 2) * Hh + o], a3 = sWa[(c + 3) * Hh + o];
#pragma unroll
    for (int nd = 0; nd < 4; nd++) {
      const float4 hv4 = *(const float4*)&sX[wv][nd][Ff + c];
      sc[nd] = fmaf(hv4.x, a0, fmaf(hv4.y, a1, fmaf(hv4.z, a2, fmaf(hv4.w, a3, sc[nd]))));
    }
  }
  float bao = ba[o], cvo = cv[o];
#pragma unroll
  for (int nd = 0; nd < 4; nd++) {
    float ap = tanhf(sc[nd] + bao) * cvo;
#pragma unroll
    for (int off = 32; off >= 1; off >>= 1) ap += __shfl_xor(ap, off, 64);
    int i = i0 + wv * 4 + nd;
    if (i < Nn) {
      if (tstep == 0) {
        ctx[(size_t)i * Hh + o] = hnreg[nd];
        if (o == 0) { mbuf[i] = ap; sbuf[i] = 1.0f; }
      } else {
        float mo = mbuf[i];
        float so = sbuf[i];
        float mn = fmaxf(mo, ap);
        float scl = expf(mo - mn);
        float p = expf(ap - mn);
        ctx[(size_t)i * Hh + o] = ctx[(size_t)i * Hh + o] * scl + p * hnreg[nd];
        if (o == 0) { mbuf[i] = mn; sbuf[i] = so * scl + p; }
      }
    }
  }
}

// ---------------- output: out[i] = (ctx/s) . Wfc + bfc ----------------
__global__ __launch_bounds__(256) void k_out(
    const float* __restrict__ ctx, const float* __restrict__ sbuf,
    const float* __restrict__ Wfc, const float* __restrict__ bfc,
    float* __restrict__ out) {
  int i = blockIdx.x * 4 + (threadIdx.x >> 6);
  if (i >= Nn) return;
  int o = threadIdx.x & 63;
  float inv = 1.0f / sbuf[i];
  float p = ctx[(size_t)i * Hh + o] * inv * Wfc[o];
#pragma unroll
  for (int off = 32; off >= 1; off >>= 1) p += __shfl_xor(p, off, 64);
  if (o == 0) out[i] = p + bfc[0];
}

extern "C" void kernel_launch(void* const* d_in, const int* in_sizes, int n_in,
                              void* d_out, int out_size, void* d_ws, size_t ws_size,
                              hipStream_t stream) {
  const float* x   = (const float*)d_in[0];
  const int* ei    = (const int*)d_in[1];
  const float* ew  = (const float*)d_in[2];
  const float* Wz  = (const float*)d_in[3];
  const float* bz  = (const float*)d_in[4];
  const float* Wr  = (const float*)d_in[5];
  const float* br  = (const float*)d_in[6];
  const float* Wh  = (const float*)d_in[7];
  const float* bh  = (const float*)d_in[8];
  const float* Wa  = (const float*)d_in[9];
  const float* ba  = (const float*)d_in[10];
  const float* cv  = (const float*)d_in[11];
  const float* Wfc = (const float*)d_in[12];
  const float* bfc = (const float*)d_in[13];
  float* out = (float*)d_out;

  char* w = (char*)d_ws;
  auto alloc = [&](size_t bytes) {
    char* p = w;
    w += (bytes + 255) & ~(size_t)255;
    return p;
  };
  float* dis = (float*)alloc((size_t)Nn * 4);       // deg, then rsqrt in place
  int* cnt   = (int*)alloc((size_t)Nn * 4);
  int* rp    = (int*)alloc((size_t)(Nn + 1) * 4);
  int* cur   = (int*)alloc((size_t)Nn * 4);
  int* csrc  = (int*)alloc((size_t)Ee * 4);
  float* cw  = (float*)alloc((size_t)Ee * 4);
  float* Pxb = (float*)alloc((size_t)Tt * Nn * Ff * 4);
  float* h   = (float*)alloc((size_t)Nn * Hh * 4);
  float* zbf = (float*)alloc((size_t)Nn * Hh * 4);
  float* rhb = (float*)alloc((size_t)Nn * Hh * 4);
  float* Ph  = (float*)alloc((size_t)Nn * Hh * 4);
  float* Prh = (float*)alloc((size_t)Nn * Hh * 4);
  float* mb  = (float*)alloc((size_t)Nn * 4);
  float* sb  = (float*)alloc((size_t)Nn * 4);
  float* ctx = (float*)alloc((size_t)Nn * Hh * 4);

  hipMemsetAsync(dis, 0, (size_t)Nn * 4, stream);
  hipMemsetAsync(cnt, 0, (size_t)Nn * 4, stream);
  hipMemsetAsync(h, 0, (size_t)Nn * Hh * 4, stream);

  k_deg<<<(Ee + 255) / 256, 256, 0, stream>>>(ei, ew, dis, cnt);
  k_dis<<<(Nn + 255) / 256, 256, 0, stream>>>(dis);
  k_scan<<<1, 1024, 0, stream>>>(cnt, rp, cur);
  k_scatter<<<(Ee + 255) / 256, 256, 0, stream>>>(ei, ew, dis, cur, csrc, cw);
  k_agg_px<<<(Nn + 3) / 4, 256, 0, stream>>>(x, Pxb, rp, csrc, cw, dis);

  const int gGemm = (Nn + 15) / 16;  // 256-thread blocks, 16 nodes each
  const int gNode = (Nn + 3) / 4;
  for (int t = 0; t < Tt; t++) {
    k_agg64<<<gNode, 256, 0, stream>>>(h, Ph, rp, csrc, cw, dis);
    k_gemm_zr<<<gGemm, 256, 0, stream>>>(Pxb, Ph, h, Wz, bz, Wr, br, zbf, rhb, t);
    k_agg64<<<gNode, 256, 0, stream>>>(rhb, Prh, rp, csrc, cw, dis);
    k_gemm_h<<<gGemm, 256, 0, stream>>>(Pxb, Prh, zbf, h, Wh, bh, Wa, ba, cv, mb, sb, ctx, t);
  }
  k_out<<<gNode, 256, 0, stream>>>(ctx, sb, Wfc, bfc, out);
}

// Round 4
// 4375.707 us; speedup vs baseline: 5.5374x; 1.4805x over previous
//
#include <hip/hip_runtime.h>
#include <hip/hip_fp16.h>
#include <math.h>

#define Nn 50000
#define Ff 16
#define Tt 12
#define Hh 64
#define Ee 1600000
#define Cc 80  // F + H

static __device__ __forceinline__ float sigmoidf_(float x) { return 1.0f / (1.0f + expf(-x)); }

// ---------------- CSR build ----------------
__global__ void k_deg(const int* __restrict__ ei, const float* __restrict__ ew,
                      float* __restrict__ deg, int* __restrict__ cnt) {
  int e = blockIdx.x * blockDim.x + threadIdx.x;
  if (e >= Ee) return;
  int d = ei[Ee + e];
  atomicAdd(&deg[d], ew[e]);
  atomicAdd(&cnt[d], 1);
}

__global__ void k_dis(float* dd) {
  int i = blockIdx.x * blockDim.x + threadIdx.x;
  if (i >= Nn) return;
  dd[i] = 1.0f / sqrtf(dd[i] + 1.0f);  // rsqrt(deg + self-loop)
}

__global__ __launch_bounds__(1024) void k_scan(const int* __restrict__ cnt,
                                               int* __restrict__ rp, int* __restrict__ cur) {
  __shared__ int ss[1024];
  const int ITEMS = (Nn + 1023) / 1024;  // 49
  int t = threadIdx.x;
  int base = t * ITEMS;
  int sum = 0;
  for (int k = 0; k < ITEMS; k++) {
    int idx = base + k;
    if (idx < Nn) sum += cnt[idx];
  }
  ss[t] = sum;
  __syncthreads();
  for (int off = 1; off < 1024; off <<= 1) {
    int v = (t >= off) ? ss[t - off] : 0;
    __syncthreads();
    ss[t] += v;
    __syncthreads();
  }
  int run = ss[t] - sum;  // exclusive prefix
  for (int k = 0; k < ITEMS; k++) {
    int idx = base + k;
    if (idx < Nn) { rp[idx] = run; cur[idx] = run; run += cnt[idx]; }
  }
  if (t == 0) rp[Nn] = Ee;
}

__global__ void k_scatter(const int* __restrict__ ei, const float* __restrict__ ew,
                          const float* __restrict__ dis, int* __restrict__ cur,
                          int* __restrict__ csrc, float* __restrict__ cw) {
  int e = blockIdx.x * blockDim.x + threadIdx.x;
  if (e >= Ee) return;
  int s = ei[e];
  int d = ei[Ee + e];
  float w = ew[e] * dis[s] * dis[d];
  int pos = atomicAdd(&cur[d], 1);
  csrc[pos] = s;
  cw[pos] = w;
}

// ---------------- x fp32 -> fp16 (once; x ~ N(0,1), no range issues) ----------------
__global__ void k_cvt_x(const float* __restrict__ x, __half* __restrict__ x16) {
  size_t idx = (size_t)blockIdx.x * blockDim.x + threadIdx.x;
  const size_t total = (size_t)Nn * Ff * Tt;
  if (idx < total) x16[idx] = __float2half(x[idx]);
}

// ---------------- Px[t][i][f] = (A_hat @ x), gather from fp16 x ----------------
__global__ __launch_bounds__(256) void k_agg_px(
    const float* __restrict__ x, const __half* __restrict__ x16, float* __restrict__ Px,
    const int* __restrict__ rp, const int* __restrict__ csrc,
    const float* __restrict__ cw, const float* __restrict__ dis) {
  int i = blockIdx.x * 4 + (threadIdx.x >> 6);
  if (i >= Nn) return;
  int lane = threadIdx.x & 63;
  const int R = Ff * Tt;  // 192
  float d = dis[i];
  float sn = d * d;
  const float* xi = x + (size_t)i * R;  // self term fp32 (exact)
  float a0 = sn * xi[lane];
  float a1 = sn * xi[64 + lane];
  float a2 = sn * xi[128 + lane];
  float b0 = 0.f, b1 = 0.f, b2 = 0.f;
  int jb = rp[i], je = rp[i + 1];
  int j = jb;
  for (; j + 2 <= je; j += 2) {
    int s0 = csrc[j], s1 = csrc[j + 1];
    float w0 = cw[j], w1 = cw[j + 1];
    const __half* x0 = x16 + (size_t)s0 * R;
    const __half* x1 = x16 + (size_t)s1 * R;
    float u0 = __half2float(x0[lane]);
    float u1 = __half2float(x0[64 + lane]);
    float u2 = __half2float(x0[128 + lane]);
    float v0 = __half2float(x1[lane]);
    float v1 = __half2float(x1[64 + lane]);
    float v2 = __half2float(x1[128 + lane]);
    a0 = fmaf(w0, u0, a0); a1 = fmaf(w0, u1, a1); a2 = fmaf(w0, u2, a2);
    b0 = fmaf(w1, v0, b0); b1 = fmaf(w1, v1, b1); b2 = fmaf(w1, v2, b2);
  }
  for (; j < je; j++) {
    int s = csrc[j];
    float w = cw[j];
    const __half* xr = x16 + (size_t)s * R;
    a0 = fmaf(w, __half2float(xr[lane]), a0);
    a1 = fmaf(w, __half2float(xr[64 + lane]), a1);
    a2 = fmaf(w, __half2float(xr[128 + lane]), a2);
  }
  a0 += b0; a1 += b1; a2 += b2;
#pragma unroll
  for (int k = 0; k < 3; k++) {
    int c = lane + 64 * k;      // c = f*T + t within the x row
    int f = c / Tt, tt = c % Tt;
    float val = (k == 0) ? a0 : (k == 1 ? a1 : a2);
    Px[(size_t)tt * Nn * Ff + (size_t)i * Ff + f] = val;
  }
}

// ---------------- fp16-gather aggregation: out = self_norm*v[i] + sum w*v[src] ----------------
__global__ __launch_bounds__(256) void k_agg64h(
    const __half* __restrict__ v, float* __restrict__ outv,
    const int* __restrict__ rp, const int* __restrict__ csrc,
    const float* __restrict__ cw, const float* __restrict__ dis) {
  int i = blockIdx.x * 4 + (threadIdx.x >> 6);
  if (i >= Nn) return;
  int o = threadIdx.x & 63;
  float d = dis[i];
  float acc0 = d * d * __half2float(v[(size_t)i * Hh + o]);
  float acc1 = 0.f;
  int jb = rp[i], je = rp[i + 1];
  int j = jb;
  for (; j + 4 <= je; j += 4) {
    int s0 = csrc[j], s1 = csrc[j + 1], s2 = csrc[j + 2], s3 = csrc[j + 3];
    float w0 = cw[j], w1 = cw[j + 1], w2 = cw[j + 2], w3 = cw[j + 3];
    float v0 = __half2float(v[(size_t)s0 * Hh + o]);
    float v1 = __half2float(v[(size_t)s1 * Hh + o]);
    float v2 = __half2float(v[(size_t)s2 * Hh + o]);
    float v3 = __half2float(v[(size_t)s3 * Hh + o]);
    acc0 = fmaf(w0, v0, acc0); acc1 = fmaf(w1, v1, acc1);
    acc0 = fmaf(w2, v2, acc0); acc1 = fmaf(w3, v3, acc1);
  }
  for (; j < je; j++) acc0 = fmaf(cw[j], __half2float(v[(size_t)csrc[j] * Hh + o]), acc0);
  outv[(size_t)i * Hh + o] = acc0 + acc1;
}

// ---------------- GEMM z/r: 256 threads, 4 waves, 16 nodes/block ----------------
__global__ __launch_bounds__(256) void k_gemm_zr(
    const float* __restrict__ Px, const float* __restrict__ Ph,
    const float* __restrict__ h,
    const float* __restrict__ Wz, const float* __restrict__ bz,
    const float* __restrict__ Wr, const float* __restrict__ br,
    float* __restrict__ zb, __half* __restrict__ rh16, int tstep) {
  __shared__ float sWz[Cc * Hh];    // 20 KB
  __shared__ float sWr[Cc * Hh];    // 20 KB
  __shared__ float sX[4][4][Cc];    // 5 KB  [wave][node][c]
  const int tid = threadIdx.x;
  const int i0 = blockIdx.x * 16;
  {
    const float4* wz4 = (const float4*)Wz;
    const float4* wr4 = (const float4*)Wr;
    float4* sz4 = (float4*)sWz;
    float4* sr4 = (float4*)sWr;
    for (int q = tid; q < (Cc * Hh) / 4; q += 256) { sz4[q] = wz4[q]; sr4[q] = wr4[q]; }
  }
  {
    float4* s4 = (float4*)&sX[0][0][0];
    const float4* px4 = (const float4*)(Px + (size_t)tstep * Nn * Ff);
    const float4* ph4 = (const float4*)Ph;
    for (int q = tid; q < 16 * 20; q += 256) {
      int n = q / 20, r = q % 20;
      int i = i0 + n;
      float4 v = make_float4(0.f, 0.f, 0.f, 0.f);
      if (i < Nn) v = (r < 4) ? px4[(size_t)i * 4 + r] : ph4[(size_t)i * 16 + (r - 4)];
      s4[q] = v;
    }
  }
  __syncthreads();
  const int wv = tid >> 6, o = tid & 63;
  float az[4] = {0, 0, 0, 0}, ar[4] = {0, 0, 0, 0};
  for (int c = 0; c < Cc; c += 4) {
    float z0 = sWz[(c + 0) * Hh + o], z1 = sWz[(c + 1) * Hh + o];
    float z2 = sWz[(c + 2) * Hh + o], z3 = sWz[(c + 3) * Hh + o];
    float r0 = sWr[(c + 0) * Hh + o], r1 = sWr[(c + 1) * Hh + o];
    float r2 = sWr[(c + 2) * Hh + o], r3 = sWr[(c + 3) * Hh + o];
#pragma unroll
    for (int nd = 0; nd < 4; nd++) {
      const float4 xv = *(const float4*)&sX[wv][nd][c];
      az[nd] = fmaf(xv.x, z0, fmaf(xv.y, z1, fmaf(xv.z, z2, fmaf(xv.w, z3, az[nd]))));
      ar[nd] = fmaf(xv.x, r0, fmaf(xv.y, r1, fmaf(xv.z, r2, fmaf(xv.w, r3, ar[nd]))));
    }
  }
  float bzo = bz[o], bro = br[o];
#pragma unroll
  for (int nd = 0; nd < 4; nd++) {
    int i = i0 + wv * 4 + nd;
    if (i < Nn) {
      float zv = sigmoidf_(az[nd] + bzo);
      float rv = sigmoidf_(ar[nd] + bro);
      float hv = h[(size_t)i * Hh + o];
      zb[(size_t)i * Hh + o] = zv;
      rh16[(size_t)i * Hh + o] = __float2half(rv * hv);
    }
  }
}

// ---------------- GEMM h: GRU update + online-softmax attention fused ----------------
__global__ __launch_bounds__(256) void k_gemm_h(
    const float* __restrict__ Px, const float* __restrict__ Prh,
    const float* __restrict__ zb, float* __restrict__ h, __half* __restrict__ h16,
    const float* __restrict__ Wh, const float* __restrict__ bh,
    const float* __restrict__ Wa, const float* __restrict__ ba,
    const float* __restrict__ cv,
    float* __restrict__ mbuf, float* __restrict__ sbuf, float* __restrict__ ctx,
    int tstep) {
  __shared__ float sWh[Cc * Hh];    // 20 KB
  __shared__ float sWa[Hh * Hh];    // 16 KB
  __shared__ float sX[4][4][Cc];    // 5 KB
  const int tid = threadIdx.x;
  const int i0 = blockIdx.x * 16;
  {
    const float4* w4 = (const float4*)Wh;
    float4* s4 = (float4*)sWh;
    for (int q = tid; q < (Cc * Hh) / 4; q += 256) s4[q] = w4[q];
    const float4* a4 = (const float4*)Wa;
    float4* sa4 = (float4*)sWa;
    for (int q = tid; q < (Hh * Hh) / 4; q += 256) sa4[q] = a4[q];
  }
  {
    float4* s4 = (float4*)&sX[0][0][0];
    const float4* px4 = (const float4*)(Px + (size_t)tstep * Nn * Ff);
    const float4* ph4 = (const float4*)Prh;
    for (int q = tid; q < 16 * 20; q += 256) {
      int n = q / 20, r = q % 20;
      int i = i0 + n;
      float4 v = make_float4(0.f, 0.f, 0.f, 0.f);
      if (i < Nn) v = (r < 4) ? px4[(size_t)i * 4 + r] : ph4[(size_t)i * 16 + (r - 4)];
      s4[q] = v;
    }
  }
  __syncthreads();
  const int wv = tid >> 6, o = tid & 63;
  float ah[4] = {0, 0, 0, 0};
  for (int c = 0; c < Cc; c += 4) {
    float w0 = sWh[(c + 0) * Hh + o], w1 = sWh[(c + 1) * Hh + o];
    float w2 = sWh[(c + 2) * Hh + o], w3 = sWh[(c + 3) * Hh + o];
#pragma unroll
    for (int nd = 0; nd < 4; nd++) {
      const float4 xv = *(const float4*)&sX[wv][nd][c];
      ah[nd] = fmaf(xv.x, w0, fmaf(xv.y, w1, fmaf(xv.z, w2, fmaf(xv.w, w3, ah[nd]))));
    }
  }
  // GRU update; store h_new to global (fp32 + fp16) + wave-private LDS row
  float bho = bh[o];
  float hnreg[4];
#pragma unroll
  for (int nd = 0; nd < 4; nd++) {
    int i = i0 + wv * 4 + nd;
    float hn = 0.f;
    if (i < Nn) {
      float hc = tanhf(ah[nd] + bho);
      float zv = zb[(size_t)i * Hh + o];
      float hv = h[(size_t)i * Hh + o];
      hn = zv * hv + (1.0f - zv) * hc;
      h[(size_t)i * Hh + o] = hn;
      h16[(size_t)i * Hh + o] = __float2half(hn);
    }
    sX[wv][nd][Ff + o] = hn;  // wave-private: no cross-wave readers
    hnreg[nd] = hn;
  }
  // attention: score = tanh(hn @ Wa + ba); align = score . cv; online softmax
  float sc[4] = {0, 0, 0, 0};
  for (int c = 0; c < Hh; c += 4) {
    float a0 = sWa[(c + 0) * Hh + o], a1 = sWa[(c + 1) * Hh + o];
    float a2 = sWa[(c + 2) * Hh + o], a3 = sWa[(c + 3) * Hh + o];
#pragma unroll
    for (int nd = 0; nd < 4; nd++) {
      const float4 hv4 = *(const float4*)&sX[wv][nd][Ff + c];
      sc[nd] = fmaf(hv4.x, a0, fmaf(hv4.y, a1, fmaf(hv4.z, a2, fmaf(hv4.w, a3, sc[nd]))));
    }
  }
  float bao = ba[o], cvo = cv[o];
#pragma unroll
  for (int nd = 0; nd < 4; nd++) {
    float ap = tanhf(sc[nd] + bao) * cvo;
#pragma unroll
    for (int off = 32; off >= 1; off >>= 1) ap += __shfl_xor(ap, off, 64);
    int i = i0 + wv * 4 + nd;
    if (i < Nn) {
      if (tstep == 0) {
        ctx[(size_t)i * Hh + o] = hnreg[nd];
        if (o == 0) { mbuf[i] = ap; sbuf[i] = 1.0f; }
      } else {
        float mo = mbuf[i];
        float so = sbuf[i];
        float mn = fmaxf(mo, ap);
        float scl = expf(mo - mn);
        float p = expf(ap - mn);
        ctx[(size_t)i * Hh + o] = ctx[(size_t)i * Hh + o] * scl + p * hnreg[nd];
        if (o == 0) { mbuf[i] = mn; sbuf[i] = so * scl + p; }
      }
    }
  }
}

// ---------------- output: out[i] = (ctx/s) . Wfc + bfc ----------------
__global__ __launch_bounds__(256) void k_out(
    const float* __restrict__ ctx, const float* __restrict__ sbuf,
    const float* __restrict__ Wfc, const float* __restrict__ bfc,
    float* __restrict__ out) {
  int i = blockIdx.x * 4 + (threadIdx.x >> 6);
  if (i >= Nn) return;
  int o = threadIdx.x & 63;
  float inv = 1.0f / sbuf[i];
  float p = ctx[(size_t)i * Hh + o] * inv * Wfc[o];
#pragma unroll
  for (int off = 32; off >= 1; off >>= 1) p += __shfl_xor(p, off, 64);
  if (o == 0) out[i] = p + bfc[0];
}

extern "C" void kernel_launch(void* const* d_in, const int* in_sizes, int n_in,
                              void* d_out, int out_size, void* d_ws, size_t ws_size,
                              hipStream_t stream) {
  const float* x   = (const float*)d_in[0];
  const int* ei    = (const int*)d_in[1];
  const float* ew  = (const float*)d_in[2];
  const float* Wz  = (const float*)d_in[3];
  const float* bz  = (const float*)d_in[4];
  const float* Wr  = (const float*)d_in[5];
  const float* br  = (const float*)d_in[6];
  const float* Wh  = (const float*)d_in[7];
  const float* bh  = (const float*)d_in[8];
  const float* Wa  = (const float*)d_in[9];
  const float* ba  = (const float*)d_in[10];
  const float* cv  = (const float*)d_in[11];
  const float* Wfc = (const float*)d_in[12];
  const float* bfc = (const float*)d_in[13];
  float* out = (float*)d_out;

  char* w = (char*)d_ws;
  auto alloc = [&](size_t bytes) {
    char* p = w;
    w += (bytes + 255) & ~(size_t)255;
    return p;
  };
  float* dis = (float*)alloc((size_t)Nn * 4);       // deg, then rsqrt in place
  int* cnt   = (int*)alloc((size_t)Nn * 4);
  int* rp    = (int*)alloc((size_t)(Nn + 1) * 4);
  int* cur   = (int*)alloc((size_t)Nn * 4);
  int* csrc  = (int*)alloc((size_t)Ee * 4);
  float* cw  = (float*)alloc((size_t)Ee * 4);
  __half* x16 = (__half*)alloc((size_t)Nn * Ff * Tt * 2);
  float* Pxb = (float*)alloc((size_t)Tt * Nn * Ff * 4);
  float* h   = (float*)alloc((size_t)Nn * Hh * 4);
  __half* h16 = (__half*)alloc((size_t)Nn * Hh * 2);
  __half* rh16 = (__half*)alloc((size_t)Nn * Hh * 2);
  float* zbf = (float*)alloc((size_t)Nn * Hh * 4);
  float* Ph  = (float*)alloc((size_t)Nn * Hh * 4);
  float* Prh = (float*)alloc((size_t)Nn * Hh * 4);
  float* mb  = (float*)alloc((size_t)Nn * 4);
  float* sb  = (float*)alloc((size_t)Nn * 4);
  float* ctx = (float*)alloc((size_t)Nn * Hh * 4);

  hipMemsetAsync(dis, 0, (size_t)Nn * 4, stream);
  hipMemsetAsync(cnt, 0, (size_t)Nn * 4, stream);
  hipMemsetAsync(h, 0, (size_t)Nn * Hh * 4, stream);
  hipMemsetAsync(h16, 0, (size_t)Nn * Hh * 2, stream);  // fp16 zero == 0x0000

  k_deg<<<(Ee + 255) / 256, 256, 0, stream>>>(ei, ew, dis, cnt);
  k_dis<<<(Nn + 255) / 256, 256, 0, stream>>>(dis);
  k_scan<<<1, 1024, 0, stream>>>(cnt, rp, cur);
  k_scatter<<<(Ee + 255) / 256, 256, 0, stream>>>(ei, ew, dis, cur, csrc, cw);
  {
    const size_t total = (size_t)Nn * Ff * Tt;
    k_cvt_x<<<(int)((total + 255) / 256), 256, 0, stream>>>(x, x16);
  }
  k_agg_px<<<(Nn + 3) / 4, 256, 0, stream>>>(x, x16, Pxb, rp, csrc, cw, dis);

  const int gGemm = (Nn + 15) / 16;  // 256-thread blocks, 16 nodes each
  const int gNode = (Nn + 3) / 4;
  for (int t = 0; t < Tt; t++) {
    k_agg64h<<<gNode, 256, 0, stream>>>(h16, Ph, rp, csrc, cw, dis);
    k_gemm_zr<<<gGemm, 256, 0, stream>>>(Pxb, Ph, h, Wz, bz, Wr, br, zbf, rh16, t);
    k_agg64h<<<gNode, 256, 0, stream>>>(rh16, Prh, rp, csrc, cw, dis);
    k_gemm_h<<<gGemm, 256, 0, stream>>>(Pxb, Prh, zbf, h, h16, Wh, bh, Wa, ba, cv, mb, sb, ctx, t);
  }
  k_out<<<gNode, 256, 0, stream>>>(ctx, sb, Wfc, bfc, out);
}

// Round 5
// 3756.787 us; speedup vs baseline: 6.4496x; 1.1647x over previous
//
#include <hip/hip_runtime.h>
#include <hip/hip_fp16.h>
#include <math.h>

#define Nn 50000
#define Ff 16
#define Tt 12
#define Hh 64
#define Ee 1600000
#define Cc 80  // F + H

static __device__ __forceinline__ float sigmoidf_(float x) { return 1.0f / (1.0f + expf(-x)); }

// ---------------- CSR build ----------------
// dc[d] accumulates (count << 42) + round(ew * 2^21) in one u64 atomic.
// max sum(ew) < 64 -> low field < 2^27 << 2^42; count < 2^22. Quant err 2.4e-7/edge.
__global__ void k_deg(const int* __restrict__ ei, const float* __restrict__ ew,
                      unsigned long long* __restrict__ dc) {
  int e = blockIdx.x * blockDim.x + threadIdx.x;
  if (e >= Ee) return;
  int d = ei[Ee + e];
  unsigned long long pk = (1ULL << 42) + (unsigned long long)(ew[e] * 2097152.0f + 0.5f);
  atomicAdd(&dc[d], pk);
}

__global__ void k_dis(const unsigned long long* __restrict__ dc,
                      float* __restrict__ dis, int* __restrict__ cnt) {
  int i = blockIdx.x * blockDim.x + threadIdx.x;
  if (i >= Nn) return;
  unsigned long long v = dc[i];
  cnt[i] = (int)(v >> 42);
  float deg = (float)(v & ((1ULL << 42) - 1)) * (1.0f / 2097152.0f);
  dis[i] = 1.0f / sqrtf(deg + 1.0f);
}

__global__ __launch_bounds__(1024) void k_scan(const int* __restrict__ cnt,
                                               int* __restrict__ rp, int* __restrict__ cur) {
  __shared__ int ss[1024];
  const int ITEMS = (Nn + 1023) / 1024;  // 49
  int t = threadIdx.x;
  int base = t * ITEMS;
  int sum = 0;
  for (int k = 0; k < ITEMS; k++) {
    int idx = base + k;
    if (idx < Nn) sum += cnt[idx];
  }
  ss[t] = sum;
  __syncthreads();
  for (int off = 1; off < 1024; off <<= 1) {
    int v = (t >= off) ? ss[t - off] : 0;
    __syncthreads();
    ss[t] += v;
    __syncthreads();
  }
  int run = ss[t] - sum;  // exclusive prefix
  for (int k = 0; k < ITEMS; k++) {
    int idx = base + k;
    if (idx < Nn) { rp[idx] = run; cur[idx] = run; run += cnt[idx]; }
  }
  if (t == 0) rp[Nn] = Ee;
}

// edge2[pos] = {src, normalized weight} packed: one scattered 8-B store per edge
__global__ void k_scatter(const int* __restrict__ ei, const float* __restrict__ ew,
                          const float* __restrict__ dis, int* __restrict__ cur,
                          int2* __restrict__ edge2) {
  int e = blockIdx.x * blockDim.x + threadIdx.x;
  if (e >= Ee) return;
  int s = ei[e];
  int d = ei[Ee + e];
  float w = ew[e] * dis[s] * dis[d];
  int pos = atomicAdd(&cur[d], 1);
  edge2[pos] = make_int2(s, __float_as_int(w));
}

// ---------------- x fp32 -> fp16 (once) ----------------
__global__ void k_cvt_x(const float* __restrict__ x, __half* __restrict__ x16) {
  size_t idx = (size_t)blockIdx.x * blockDim.x + threadIdx.x;
  const size_t total = (size_t)Nn * Ff * Tt;
  if (idx < total) x16[idx] = __float2half(x[idx]);
}

// ---------------- Px16[t][i][f] = (A_hat @ x): wave per node, 48 lanes x 8B per edge ----------------
__global__ __launch_bounds__(256) void k_agg_px(
    const float* __restrict__ x, const __half* __restrict__ x16, __half* __restrict__ Px16,
    const int* __restrict__ rp, const int2* __restrict__ edge2,
    const float* __restrict__ dis) {
  int i = blockIdx.x * 4 + (threadIdx.x >> 6);
  if (i >= Nn) return;
  int lane = threadIdx.x & 63;
  const int R = Ff * Tt;  // 192
  const bool act = lane < 48;
  float d = dis[i], sn = d * d;
  float a0 = 0.f, a1 = 0.f, a2 = 0.f, a3 = 0.f;
  if (act) {
    float4 sv = *(const float4*)(x + (size_t)i * R + 4 * lane);  // self, fp32 exact
    a0 = sn * sv.x; a1 = sn * sv.y; a2 = sn * sv.z; a3 = sn * sv.w;
  }
  int jb = rp[i], je = rp[i + 1];
  for (int j = jb; j < je; j += 2) {
    int jc1 = min(j + 1, Ee - 1);
    int2 e0 = edge2[j];
    int2 e1 = edge2[jc1];
    float w0 = __int_as_float(e0.y);
    float w1 = (j + 1 < je) ? __int_as_float(e1.y) : 0.f;
    if (act) {
      uint2 g0 = *(const uint2*)(x16 + (size_t)e0.x * R + 4 * lane);
      uint2 g1 = *(const uint2*)(x16 + (size_t)e1.x * R + 4 * lane);
      float2 p01 = __half22float2(*reinterpret_cast<const __half2*>(&g0.x));
      float2 p23 = __half22float2(*reinterpret_cast<const __half2*>(&g0.y));
      float2 q01 = __half22float2(*reinterpret_cast<const __half2*>(&g1.x));
      float2 q23 = __half22float2(*reinterpret_cast<const __half2*>(&g1.y));
      a0 = fmaf(w0, p01.x, a0); a1 = fmaf(w0, p01.y, a1);
      a2 = fmaf(w0, p23.x, a2); a3 = fmaf(w0, p23.y, a3);
      a0 = fmaf(w1, q01.x, a0); a1 = fmaf(w1, q01.y, a1);
      a2 = fmaf(w1, q23.x, a2); a3 = fmaf(w1, q23.y, a3);
    }
  }
  if (act) {
#pragma unroll
    for (int k = 0; k < 4; k++) {
      int cch = 4 * lane + k;           // channel = f*T + t
      int f = cch / Tt, tt = cch % Tt;
      float val = (k == 0) ? a0 : (k == 1) ? a1 : (k == 2) ? a2 : a3;
      Px16[(size_t)tt * Nn * Ff + (size_t)i * Ff + f] = __float2half(val);
    }
  }
}

// ---------------- aggregation: wave per node, 16 lanes/edge x 8B, 4 edges/instr ----------------
__global__ __launch_bounds__(256) void k_agg64v(
    const __half* __restrict__ v, __half* __restrict__ outv,
    const int* __restrict__ rp, const int2* __restrict__ edge2,
    const float* __restrict__ dis) {
  int i = blockIdx.x * 4 + (threadIdx.x >> 6);
  if (i >= Nn) return;
  int lane = threadIdx.x & 63;
  int g = lane >> 4;   // edge slot 0..3
  int c = lane & 15;   // channel quad: 4c..4c+3
  float d = dis[i], sn = d * d;
  float a0, a1, a2, a3;
  {
    const uint2 gv = *(const uint2*)(v + (size_t)i * Hh + 4 * c);  // self
    float2 f01 = __half22float2(*reinterpret_cast<const __half2*>(&gv.x));
    float2 f23 = __half22float2(*reinterpret_cast<const __half2*>(&gv.y));
    float ws = (g == 0) ? sn : 0.f;
    a0 = ws * f01.x; a1 = ws * f01.y; a2 = ws * f23.x; a3 = ws * f23.y;
  }
  int jb = rp[i], je = rp[i + 1];
  for (int j0 = jb; j0 < je; j0 += 8) {
    int j1 = j0 + g;
    int j2 = j0 + 4 + g;
    int2 e1 = edge2[min(j1, Ee - 1)];
    int2 e2 = edge2[min(j2, Ee - 1)];
    float w1 = (j1 < je) ? __int_as_float(e1.y) : 0.f;
    float w2 = (j2 < je) ? __int_as_float(e2.y) : 0.f;
    const uint2 g1 = *(const uint2*)(v + (size_t)e1.x * Hh + 4 * c);
    const uint2 g2 = *(const uint2*)(v + (size_t)e2.x * Hh + 4 * c);
    float2 p01 = __half22float2(*reinterpret_cast<const __half2*>(&g1.x));
    float2 p23 = __half22float2(*reinterpret_cast<const __half2*>(&g1.y));
    float2 q01 = __half22float2(*reinterpret_cast<const __half2*>(&g2.x));
    float2 q23 = __half22float2(*reinterpret_cast<const __half2*>(&g2.y));
    a0 = fmaf(w1, p01.x, a0); a1 = fmaf(w1, p01.y, a1);
    a2 = fmaf(w1, p23.x, a2); a3 = fmaf(w1, p23.y, a3);
    a0 = fmaf(w2, q01.x, a0); a1 = fmaf(w2, q01.y, a1);
    a2 = fmaf(w2, q23.x, a2); a3 = fmaf(w2, q23.y, a3);
  }
  // reduce across the 4 edge groups (lane strides 16, 32)
  a0 += __shfl_xor(a0, 16, 64); a1 += __shfl_xor(a1, 16, 64);
  a2 += __shfl_xor(a2, 16, 64); a3 += __shfl_xor(a3, 16, 64);
  a0 += __shfl_xor(a0, 32, 64); a1 += __shfl_xor(a1, 32, 64);
  a2 += __shfl_xor(a2, 32, 64); a3 += __shfl_xor(a3, 32, 64);
  if (lane < 16) {
    __half2 h01, h23;
    h01.x = __float2half_rn(a0); h01.y = __float2half_rn(a1);
    h23.x = __float2half_rn(a2); h23.y = __float2half_rn(a3);
    uint2 st;
    st.x = *reinterpret_cast<unsigned int*>(&h01);
    st.y = *reinterpret_cast<unsigned int*>(&h23);
    *(uint2*)(outv + (size_t)i * Hh + 4 * c) = st;
  }
}

// shared helper: stage 16 nodes x 80 channels (fp16 sources) into fp32 LDS
static __device__ __forceinline__ void stage_x(
    float (*sX)[Cc], const __half* __restrict__ Px16t, const __half* __restrict__ P64,
    int i0, int tid) {
  if (tid < 160) {
    int n = tid / 10, r = tid % 10;
    int i = i0 + n;
    uint4 raw = make_uint4(0u, 0u, 0u, 0u);
    if (i < Nn) {
      raw = (r < 2) ? *(const uint4*)(Px16t + (size_t)i * Ff + r * 8)
                    : *(const uint4*)(P64 + (size_t)i * Hh + (r - 2) * 8);
    }
    float2 f0 = __half22float2(*reinterpret_cast<const __half2*>(&raw.x));
    float2 f1 = __half22float2(*reinterpret_cast<const __half2*>(&raw.y));
    float2 f2 = __half22float2(*reinterpret_cast<const __half2*>(&raw.z));
    float2 f3 = __half22float2(*reinterpret_cast<const __half2*>(&raw.w));
    float* dst = &sX[n][r * 8];
    dst[0] = f0.x; dst[1] = f0.y; dst[2] = f1.x; dst[3] = f1.y;
    dst[4] = f2.x; dst[5] = f2.y; dst[6] = f3.x; dst[7] = f3.y;
  }
}

// ---------------- GEMM z/r: 256 threads, 4 waves, 16 nodes/block ----------------
__global__ __launch_bounds__(256) void k_gemm_zr(
    const __half* __restrict__ Px16, const __half* __restrict__ Ph16,
    const __half* __restrict__ h16,
    const float* __restrict__ Wz, const float* __restrict__ bz,
    const float* __restrict__ Wr, const float* __restrict__ br,
    __half* __restrict__ zb16, __half* __restrict__ rh16, int tstep) {
  __shared__ float sWz[Cc * Hh];    // 20 KB
  __shared__ float sWr[Cc * Hh];    // 20 KB
  __shared__ float sX[16][Cc];      // 5 KB
  const int tid = threadIdx.x;
  const int i0 = blockIdx.x * 16;
  {
    const float4* wz4 = (const float4*)Wz;
    const float4* wr4 = (const float4*)Wr;
    float4* sz4 = (float4*)sWz;
    float4* sr4 = (float4*)sWr;
    for (int q = tid; q < (Cc * Hh) / 4; q += 256) { sz4[q] = wz4[q]; sr4[q] = wr4[q]; }
  }
  stage_x(sX, Px16 + (size_t)tstep * Nn * Ff, Ph16, i0, tid);
  __syncthreads();
  const int wv = tid >> 6, o = tid & 63;
  float az[4] = {0, 0, 0, 0}, ar[4] = {0, 0, 0, 0};
  for (int c = 0; c < Cc; c += 4) {
    float z0 = sWz[(c + 0) * Hh + o], z1 = sWz[(c + 1) * Hh + o];
    float z2 = sWz[(c + 2) * Hh + o], z3 = sWz[(c + 3) * Hh + o];
    float r0 = sWr[(c + 0) * Hh + o], r1 = sWr[(c + 1) * Hh + o];
    float r2 = sWr[(c + 2) * Hh + o], r3 = sWr[(c + 3) * Hh + o];
#pragma unroll
    for (int nd = 0; nd < 4; nd++) {
      const float4 xv = *(const float4*)&sX[wv * 4 + nd][c];
      az[nd] = fmaf(xv.x, z0, fmaf(xv.y, z1, fmaf(xv.z, z2, fmaf(xv.w, z3, az[nd]))));
      ar[nd] = fmaf(xv.x, r0, fmaf(xv.y, r1, fmaf(xv.z, r2, fmaf(xv.w, r3, ar[nd]))));
    }
  }
  float bzo = bz[o], bro = br[o];
#pragma unroll
  for (int nd = 0; nd < 4; nd++) {
    int i = i0 + wv * 4 + nd;
    if (i < Nn) {
      float zv = sigmoidf_(az[nd] + bzo);
      float rv = sigmoidf_(ar[nd] + bro);
      float hv = __half2float(h16[(size_t)i * Hh + o]);
      zb16[(size_t)i * Hh + o] = __float2half(zv);
      rh16[(size_t)i * Hh + o] = __float2half(rv * hv);
    }
  }
}

// ---------------- GEMM h: GRU update + online-softmax attention fused ----------------
__global__ __launch_bounds__(256) void k_gemm_h(
    const __half* __restrict__ Px16, const __half* __restrict__ Prh16,
    const __half* __restrict__ zb16, float* __restrict__ h, __half* __restrict__ h16,
    const float* __restrict__ Wh, const float* __restrict__ bh,
    const float* __restrict__ Wa, const float* __restrict__ ba,
    const float* __restrict__ cv,
    float* __restrict__ mbuf, float* __restrict__ sbuf, float* __restrict__ ctx,
    int tstep) {
  __shared__ float sWh[Cc * Hh];    // 20 KB
  __shared__ float sWa[Hh * Hh];    // 16 KB
  __shared__ float sX[16][Cc];      // 5 KB
  const int tid = threadIdx.x;
  const int i0 = blockIdx.x * 16;
  {
    const float4* w4 = (const float4*)Wh;
    float4* s4 = (float4*)sWh;
    for (int q = tid; q < (Cc * Hh) / 4; q += 256) s4[q] = w4[q];
    const float4* a4 = (const float4*)Wa;
    float4* sa4 = (float4*)sWa;
    for (int q = tid; q < (Hh * Hh) / 4; q += 256) sa4[q] = a4[q];
  }
  stage_x(sX, Px16 + (size_t)tstep * Nn * Ff, Prh16, i0, tid);
  __syncthreads();
  const int wv = tid >> 6, o = tid & 63;
  float ah[4] = {0, 0, 0, 0};
  for (int c = 0; c < Cc; c += 4) {
    float w0 = sWh[(c + 0) * Hh + o], w1 = sWh[(c + 1) * Hh + o];
    float w2 = sWh[(c + 2) * Hh + o], w3 = sWh[(c + 3) * Hh + o];
#pragma unroll
    for (int nd = 0; nd < 4; nd++) {
      const float4 xv = *(const float4*)&sX[wv * 4 + nd][c];
      ah[nd] = fmaf(xv.x, w0, fmaf(xv.y, w1, fmaf(xv.z, w2, fmaf(xv.w, w3, ah[nd]))));
    }
  }
  // GRU update; h fp32 master + fp16 shadow; stash h_new in wave-private LDS row
  float bho = bh[o];
  float hnreg[4];
#pragma unroll
  for (int nd = 0; nd < 4; nd++) {
    int i = i0 + wv * 4 + nd;
    float hn = 0.f;
    if (i < Nn) {
      float hc = tanhf(ah[nd] + bho);
      float zv = __half2float(zb16[(size_t)i * Hh + o]);
      float hv = h[(size_t)i * Hh + o];
      hn = zv * hv + (1.0f - zv) * hc;
      h[(size_t)i * Hh + o] = hn;
      h16[(size_t)i * Hh + o] = __float2half(hn);
    }
    sX[wv * 4 + nd][Ff + o] = hn;  // wave-private; GEMM phase done
    hnreg[nd] = hn;
  }
  // attention: score = tanh(hn @ Wa + ba); align = score . cv; online softmax
  float sc[4] = {0, 0, 0, 0};
  for (int c = 0; c < Hh; c += 4) {
    float a0 = sWa[(c + 0) * Hh + o], a1 = sWa[(c + 1) * Hh + o];
    float a2 = sWa[(c + 2) * Hh + o], a3 = sWa[(c + 3) * Hh + o];
#pragma unroll
    for (int nd = 0; nd < 4; nd++) {
      const float4 hv4 = *(const float4*)&sX[wv * 4 + nd][Ff + c];
      sc[nd] = fmaf(hv4.x, a0, fmaf(hv4.y, a1, fmaf(hv4.z, a2, fmaf(hv4.w, a3, sc[nd]))));
    }
  }
  float bao = ba[o], cvo = cv[o];
#pragma unroll
  for (int nd = 0; nd < 4; nd++) {
    float ap = tanhf(sc[nd] + bao) * cvo;
#pragma unroll
    for (int off = 32; off >= 1; off >>= 1) ap += __shfl_xor(ap, off, 64);
    int i = i0 + wv * 4 + nd;
    if (i < Nn) {
      if (tstep == 0) {
        ctx[(size_t)i * Hh + o] = hnreg[nd];
        if (o == 0) { mbuf[i] = ap; sbuf[i] = 1.0f; }
      } else {
        float mo = mbuf[i];
        float so = sbuf[i];
        float mn = fmaxf(mo, ap);
        float scl = expf(mo - mn);
        float p = expf(ap - mn);
        ctx[(size_t)i * Hh + o] = ctx[(size_t)i * Hh + o] * scl + p * hnreg[nd];
        if (o == 0) { mbuf[i] = mn; sbuf[i] = so * scl + p; }
      }
    }
  }
}

// ---------------- output: out[i] = (ctx/s) . Wfc + bfc ----------------
__global__ __launch_bounds__(256) void k_out(
    const float* __restrict__ ctx, const float* __restrict__ sbuf,
    const float* __restrict__ Wfc, const float* __restrict__ bfc,
    float* __restrict__ out) {
  int i = blockIdx.x * 4 + (threadIdx.x >> 6);
  if (i >= Nn) return;
  int o = threadIdx.x & 63;
  float inv = 1.0f / sbuf[i];
  float p = ctx[(size_t)i * Hh + o] * inv * Wfc[o];
#pragma unroll
  for (int off = 32; off >= 1; off >>= 1) p += __shfl_xor(p, off, 64);
  if (o == 0) out[i] = p + bfc[0];
}

extern "C" void kernel_launch(void* const* d_in, const int* in_sizes, int n_in,
                              void* d_out, int out_size, void* d_ws, size_t ws_size,
                              hipStream_t stream) {
  const float* x   = (const float*)d_in[0];
  const int* ei    = (const int*)d_in[1];
  const float* ew  = (const float*)d_in[2];
  const float* Wz  = (const float*)d_in[3];
  const float* bz  = (const float*)d_in[4];
  const float* Wr  = (const float*)d_in[5];
  const float* br  = (const float*)d_in[6];
  const float* Wh  = (const float*)d_in[7];
  const float* bh  = (const float*)d_in[8];
  const float* Wa  = (const float*)d_in[9];
  const float* ba  = (const float*)d_in[10];
  const float* cv  = (const float*)d_in[11];
  const float* Wfc = (const float*)d_in[12];
  const float* bfc = (const float*)d_in[13];
  float* out = (float*)d_out;

  char* w = (char*)d_ws;
  auto alloc = [&](size_t bytes) {
    char* p = w;
    w += (bytes + 255) & ~(size_t)255;
    return p;
  };
  unsigned long long* dc = (unsigned long long*)alloc((size_t)Nn * 8);
  float* dis = (float*)alloc((size_t)Nn * 4);
  int* cnt   = (int*)alloc((size_t)Nn * 4);
  int* rp    = (int*)alloc((size_t)(Nn + 1) * 4);
  int* cur   = (int*)alloc((size_t)Nn * 4);
  int2* edge2 = (int2*)alloc((size_t)Ee * 8);
  __half* x16  = (__half*)alloc((size_t)Nn * Ff * Tt * 2);
  __half* Px16 = (__half*)alloc((size_t)Tt * Nn * Ff * 2);
  float* h     = (float*)alloc((size_t)Nn * Hh * 4);
  __half* h16  = (__half*)alloc((size_t)Nn * Hh * 2);
  __half* rh16 = (__half*)alloc((size_t)Nn * Hh * 2);
  __half* zb16 = (__half*)alloc((size_t)Nn * Hh * 2);
  __half* Ph16 = (__half*)alloc((size_t)Nn * Hh * 2);
  __half* Prh16 = (__half*)alloc((size_t)Nn * Hh * 2);
  float* mb  = (float*)alloc((size_t)Nn * 4);
  float* sb  = (float*)alloc((size_t)Nn * 4);
  float* ctx = (float*)alloc((size_t)Nn * Hh * 4);

  hipMemsetAsync(dc, 0, (size_t)Nn * 8, stream);
  hipMemsetAsync(h, 0, (size_t)Nn * Hh * 4, stream);
  hipMemsetAsync(h16, 0, (size_t)Nn * Hh * 2, stream);  // fp16 zero == 0x0000

  k_deg<<<(Ee + 255) / 256, 256, 0, stream>>>(ei, ew, dc);
  k_dis<<<(Nn + 255) / 256, 256, 0, stream>>>(dc, dis, cnt);
  k_scan<<<1, 1024, 0, stream>>>(cnt, rp, cur);
  k_scatter<<<(Ee + 255) / 256, 256, 0, stream>>>(ei, ew, dis, cur, edge2);
  {
    const size_t total = (size_t)Nn * Ff * Tt;
    k_cvt_x<<<(int)((total + 255) / 256), 256, 0, stream>>>(x, x16);
  }
  k_agg_px<<<(Nn + 3) / 4, 256, 0, stream>>>(x, x16, Px16, rp, edge2, dis);

  const int gGemm = (Nn + 15) / 16;  // 256-thread blocks, 16 nodes each
  const int gNode = (Nn + 3) / 4;
  for (int t = 0; t < Tt; t++) {
    k_agg64v<<<gNode, 256, 0, stream>>>(h16, Ph16, rp, edge2, dis);
    k_gemm_zr<<<gGemm, 256, 0, stream>>>(Px16, Ph16, h16, Wz, bz, Wr, br, zb16, rh16, t);
    k_agg64v<<<gNode, 256, 0, stream>>>(rh16, Prh16, rp, edge2, dis);
    k_gemm_h<<<gGemm, 256, 0, stream>>>(Px16, Prh16, zb16, h, h16, Wh, bh, Wa, ba, cv,
                                        mb, sb, ctx, t);
  }
  k_out<<<gNode, 256, 0, stream>>>(ctx, sb, Wfc, bfc, out);
}